// Round 10
// baseline (365.340 us; speedup 1.0000x reference)
//
#include <hip/hip_runtime.h>

#define D 128
#define NN 50000
#define NS 20000
#define NNP 50048              // padded to multiple of 64 rows
#define NSP 20032
#define L_TOT (3 * NN + 2 * NS)
#define SCAN_CHUNK 1024
#define SCAN_NBLK ((L_TOT + SCAN_CHUNK - 1) / SCAN_CHUNK)
#define LDA 136                // LDS row stride in bf16 elems

typedef short s16x8 __attribute__((ext_vector_type(8)));
typedef float f32x4 __attribute__((ext_vector_type(4)));

__device__ __forceinline__ float b2f(unsigned int u) {
    u <<= 16;
    float f; __builtin_memcpy(&f, &u, 4);
    return f;
}
__device__ __forceinline__ unsigned short f2b(float f) {
    unsigned int u; __builtin_memcpy(&u, &f, 4);
    u += 0x7fffu + ((u >> 16) & 1u);       // RNE
    return (unsigned short)(u >> 16);
}
__device__ __forceinline__ void acc8(float* a, uint4 v) {
    a[0] += b2f(v.x & 0xffffu); a[1] += b2f(v.x >> 16);
    a[2] += b2f(v.y & 0xffffu); a[3] += b2f(v.y >> 16);
    a[4] += b2f(v.z & 0xffffu); a[5] += b2f(v.z >> 16);
    a[6] += b2f(v.w & 0xffffu); a[7] += b2f(v.w >> 16);
}

// ---------------------------------------------------------------------------
// fused prep + hist. counts must be pre-zeroed (hipMemsetAsync).
// ---------------------------------------------------------------------------
#define NX4 (NN * D / 4)                   // 1,600,000
#define NW  (5 * 16384)                    // 81,920
#define PREP_N (NX4 + NW)
#define PREP_BLOCKS ((PREP_N + 255) / 256) // 6570

struct PrepHistArgs {
    const float* x; unsigned short* xb;
    const float* w[5]; unsigned short* wt[5];
    const int* s0; const int* s1; const int* s2; const int* s3; const int* s4;
    int* counts; int* rank;
    int nE, eS;
};
__global__ __launch_bounds__(256) void preph_k(PrepHistArgs p)
{
    int bid = blockIdx.x;
    if (bid < PREP_BLOCKS) {
        int i = bid * 256 + threadIdx.x;
        if (i < NX4) {
            float4 v = ((const float4*)p.x)[i];
            ushort4 o;
            o.x = f2b(v.x); o.y = f2b(v.y); o.z = f2b(v.z); o.w = f2b(v.w);
            ((ushort4*)p.xb)[i] = o;
            return;
        }
        i -= NX4;
        if (i < NW) {
            int wi = i >> 14;
            int r  = i & 16383;
            int k = r >> 7, n = r & 127;
            p.wt[wi][n * 128 + k] = f2b(p.w[wi][k * 128 + n]);
        }
        return;
    }
    int e = (bid - PREP_BLOCKS) * 256 + threadIdx.x;
    int seg, base;
    if (e < p.nE) { seg = p.s0[e]; base = 0; }
    else {
        int r = e - p.nE;
        if      (r <     p.eS) { seg = p.s1[r];            base = NN; }
        else if (r < 2 * p.eS) { seg = p.s2[r - p.eS];     base = NN + NS; }
        else if (r < 3 * p.eS) { seg = p.s3[r - 2 * p.eS]; base = 2 * NN + NS; }
        else if (r < 4 * p.eS) { seg = p.s4[r - 3 * p.eS]; base = 2 * NN + 2 * NS; }
        else return;
    }
    p.rank[e] = atomicAdd(&p.counts[base + seg], 1);
}

// ---------------------------------------------------------------------------
// scan over concatenated counts
// ---------------------------------------------------------------------------
__global__ __launch_bounds__(256) void reduce_k(const int* __restrict__ counts,
                                                int* __restrict__ blockSums, int n)
{
    __shared__ int lds[4];
    int tid = threadIdx.x;
    int base = blockIdx.x * SCAN_CHUNK;
    int s = 0;
    #pragma unroll
    for (int i = 0; i < 4; ++i) {
        int idx = base + tid + i * 256;
        if (idx < n) s += counts[idx];
    }
    #pragma unroll
    for (int off = 32; off > 0; off >>= 1) s += __shfl_down(s, off, 64);
    if ((tid & 63) == 0) lds[tid >> 6] = s;
    __syncthreads();
    if (tid == 0) blockSums[blockIdx.x] = lds[0] + lds[1] + lds[2] + lds[3];
}

__global__ __launch_bounds__(256) void scan_sums_k(int* __restrict__ blockSums, int nb)
{
    __shared__ int lds[256];
    int tid = threadIdx.x;
    lds[tid] = (tid < nb) ? blockSums[tid] : 0;
    __syncthreads();
    for (int off = 1; off < 256; off <<= 1) {
        int t = (tid >= off) ? lds[tid - off] : 0;
        __syncthreads();
        lds[tid] += t;
        __syncthreads();
    }
    if (tid < nb) blockSums[tid] = (tid > 0) ? lds[tid - 1] : 0;
}

__global__ __launch_bounds__(256) void scan_write_k(
    const int* __restrict__ counts, const int* __restrict__ blockSums,
    int* __restrict__ offsets, int n)
{
    __shared__ int lds[256];
    int tid = threadIdx.x;
    int base = blockIdx.x * SCAN_CHUNK + tid * 4;
    int v[4]; int s = 0;
    #pragma unroll
    for (int i = 0; i < 4; ++i) {
        int idx = base + i;
        int c = (idx < n) ? counts[idx] : 0;
        v[i] = c; s += c;
    }
    lds[tid] = s;
    __syncthreads();
    for (int off = 1; off < 256; off <<= 1) {
        int t = (tid >= off) ? lds[tid - off] : 0;
        __syncthreads();
        lds[tid] += t;
        __syncthreads();
    }
    int run = blockSums[blockIdx.x] + (tid > 0 ? lds[tid - 1] : 0);
    #pragma unroll
    for (int i = 0; i < 4; ++i) {
        int idx = base + i;
        run += v[i];
        if (idx < n) offsets[idx + 1] = run;
    }
    if (blockIdx.x == 0 && tid == 0) offsets[0] = 0;
}

__global__ __launch_bounds__(256) void fill5_k(
    const int* __restrict__ s0, const int* __restrict__ v0,
    const int* __restrict__ s1, const int* __restrict__ v1,
    const int* __restrict__ s2, const int* __restrict__ v2,
    const int* __restrict__ s3, const int* __restrict__ v3,
    const int* __restrict__ s4, const int* __restrict__ v4,
    const int* __restrict__ offsets, const int* __restrict__ rank,
    int* __restrict__ perm, int nE, int eS)
{
    int e = blockIdx.x * 256 + threadIdx.x;
    int seg, val, base;
    if (e < nE) { seg = s0[e]; val = v0[e]; base = 0; }
    else {
        int r = e - nE;
        if      (r <     eS) { seg = s1[r];          val = v1[r];          base = NN; }
        else if (r < 2 * eS) { seg = s2[r - eS];     val = v2[r - eS];     base = NN + NS; }
        else if (r < 3 * eS) { seg = s3[r - 2 * eS]; val = v3[r - 2 * eS]; base = 2 * NN + NS; }
        else if (r < 4 * eS) { seg = s4[r - 3 * eS]; val = v4[r - 3 * eS]; base = 2 * NN + 2 * NS; }
        else return;
    }
    perm[offsets[base + seg] + rank[e]] = val;
}

// ---------------------------------------------------------------------------
// Fused gather + MFMA GEMM, low-LDS. Gather edge loop unrolled x8 with all
// 8 row-loads issued before accumulation (deep MLP; gathers are latency-bound
// per R7-R9 counters: FETCH ~1.1 TB/s << HBM peak, VALUBusy ~14%).
// ---------------------------------------------------------------------------
__global__ __launch_bounds__(256, 6) void gg_k(
    const unsigned short* __restrict__ feat, const int* __restrict__ offsets,
    const int* __restrict__ perm, const unsigned short* __restrict__ addend,
    const unsigned short* __restrict__ Wt, const float* __restrict__ bias,
    const unsigned short* __restrict__ Rb,
    float* __restrict__ outF, unsigned short* __restrict__ outB,
    int M, int relu)
{
    __shared__ unsigned short a_lds[64 * LDA];    // 17.4 KB

    const int tid = threadIdx.x;
    const int r0  = blockIdx.x * 64;

    // gather 64 rows: 4 passes x (16 segments x 16 lanes)
    const uint4* f4 = (const uint4*)feat;         // one row = 16 uint4
    const int lane16 = tid & 15;
    #pragma unroll
    for (int p = 0; p < 4; ++p) {
        int rloc = p * 16 + (tid >> 4);
        int s = r0 + rloc;
        float a[8] = {0.f, 0.f, 0.f, 0.f, 0.f, 0.f, 0.f, 0.f};
        if (s < M) {
            float b[8] = {0.f, 0.f, 0.f, 0.f, 0.f, 0.f, 0.f, 0.f};
            if (addend) {
                uint4 v = ((const uint4*)(addend + (size_t)s * D))[lane16];
                acc8(a, v);
            }
            int beg = offsets[s], end = offsets[s + 1];
            int j = beg;
            for (; j + 7 < end; j += 8) {
                uint4 v0 = f4[(size_t)perm[j]     * 16 + lane16];
                uint4 v1 = f4[(size_t)perm[j + 1] * 16 + lane16];
                uint4 v2 = f4[(size_t)perm[j + 2] * 16 + lane16];
                uint4 v3 = f4[(size_t)perm[j + 3] * 16 + lane16];
                uint4 v4v = f4[(size_t)perm[j + 4] * 16 + lane16];
                uint4 v5 = f4[(size_t)perm[j + 5] * 16 + lane16];
                uint4 v6 = f4[(size_t)perm[j + 6] * 16 + lane16];
                uint4 v7 = f4[(size_t)perm[j + 7] * 16 + lane16];
                acc8(a, v0); acc8(b, v1); acc8(a, v2); acc8(b, v3);
                acc8(a, v4v); acc8(b, v5); acc8(a, v6); acc8(b, v7);
            }
            if (j + 3 < end) {
                uint4 v0 = f4[(size_t)perm[j]     * 16 + lane16];
                uint4 v1 = f4[(size_t)perm[j + 1] * 16 + lane16];
                uint4 v2 = f4[(size_t)perm[j + 2] * 16 + lane16];
                uint4 v3 = f4[(size_t)perm[j + 3] * 16 + lane16];
                acc8(a, v0); acc8(b, v1); acc8(a, v2); acc8(b, v3);
                j += 4;
            }
            for (; j < end; ++j)
                acc8(a, f4[(size_t)perm[j] * 16 + lane16]);
            #pragma unroll
            for (int i = 0; i < 8; ++i) a[i] += b[i];
        }
        uint4 o;
        o.x = (unsigned int)f2b(a[0]) | ((unsigned int)f2b(a[1]) << 16);
        o.y = (unsigned int)f2b(a[2]) | ((unsigned int)f2b(a[3]) << 16);
        o.z = (unsigned int)f2b(a[4]) | ((unsigned int)f2b(a[5]) << 16);
        o.w = (unsigned int)f2b(a[6]) | ((unsigned int)f2b(a[7]) << 16);
        *((uint4*)&a_lds[rloc * LDA + lane16 * 8]) = o;
    }
    __syncthreads();

    const int lane = tid & 63;
    const int w    = tid >> 6;
    const int ln   = lane & 15;
    const int quad = lane >> 4;

    s16x8 af[4];
    const unsigned short* arow = &a_lds[(w * 16 + ln) * LDA + quad * 8];
    #pragma unroll
    for (int kc = 0; kc < 4; ++kc)
        af[kc] = *((const s16x8*)(arow + kc * 32));

    const int rbase = r0 + w * 16 + quad * 4;
    const s16x8* wt8 = (const s16x8*)Wt;          // row = 16 x s16x8

    #pragma unroll
    for (int nt = 0; nt < 8; ++nt) {
        f32x4 acc = {0.f, 0.f, 0.f, 0.f};
        const s16x8* brow = wt8 + (nt * 16 + ln) * 16 + quad;
        #pragma unroll
        for (int kc = 0; kc < 4; ++kc) {
            s16x8 bf = brow[kc * 4];              // global, L2-hit
            acc = __builtin_amdgcn_mfma_f32_16x16x32_bf16(af[kc], bf, acc, 0, 0, 0);
        }
        int col = nt * 16 + ln;
        float bc = bias[col];
        #pragma unroll
        for (int r = 0; r < 4; ++r) {
            int row = rbase + r;
            if (row < M) {
                float v = acc[r] + bc;
                size_t gi = (size_t)row * D + col;
                if (Rb) v += b2f((unsigned int)Rb[gi]);
                if (relu) v = fmaxf(v, 0.f);
                if (outF) outF[gi] = v;
                if (outB) outB[gi] = f2b(v);
            }
        }
    }
}

// ---------------------------------------------------------------------------
extern "C" void kernel_launch(void* const* d_in, const int* in_sizes, int n_in,
                              void* d_out, int out_size, void* d_ws, size_t ws_size,
                              hipStream_t stream)
{
    const float* x     = (const float*)d_in[0];
    const float* Wm    = (const float*)d_in[1];
    const float* bm    = (const float*)d_in[2];
    const float* Wn2s0 = (const float*)d_in[3];
    const float* bn2s0 = (const float*)d_in[4];
    const float* Ws2n0 = (const float*)d_in[5];
    const float* bs2n0 = (const float*)d_in[6];
    const float* Wn2s1 = (const float*)d_in[7];
    const float* bn2s1 = (const float*)d_in[8];
    const float* Ws2n1 = (const float*)d_in[9];
    const float* bs2n1 = (const float*)d_in[10];
    const int* nei  = (const int*)d_in[11];
    const int* row0 = (const int*)d_in[12];
    const int* col0 = (const int*)d_in[13];
    const int* row1 = (const int*)d_in[14];
    const int* col1 = (const int*)d_in[15];

    const int N_E = in_sizes[11] / 2;  // 600000
    const int E_S = in_sizes[12];      // 120000
    const int TOT_E = N_E + 4 * E_S;

    const int* src = nei;
    const int* dst = nei + N_E;

    float* out = (float*)d_out;

    // ---- workspace layout ----
    unsigned short* xb   = (unsigned short*)d_ws;          // x bf16 / out_l0 bf16
    unsigned short* hbf  = xb  + (size_t)NNP * D;          // h bf16 (residual)
    unsigned short* subb = hbf + (size_t)NNP * D;          // sub bf16
    unsigned short* wtb  = subb + (size_t)NSP * D;         // 5 transposed bf16 W
    int* ip      = (int*)(wtb + 5 * 16384);
    int* counts  = ip;              ip += L_TOT;
    int* offsets = ip;              ip += L_TOT + 1;
    int* rank    = ip;              ip += TOT_E;
    int* perm    = ip;              ip += TOT_E;
    int* bsums   = ip;              ip += 256;

    unsigned short* wt0 = wtb;
    unsigned short* wt1 = wtb + 16384;
    unsigned short* wt2 = wtb + 2 * 16384;
    unsigned short* wt3 = wtb + 3 * 16384;
    unsigned short* wt4 = wtb + 4 * 16384;

    const int* offB  = offsets;
    const int* off0c = offsets + NN;
    const int* off0r = offsets + NN + NS;
    const int* off1c = offsets + 2 * NN + NS;
    const int* off1r = offsets + 2 * NN + 2 * NS;

    dim3 blk(256);
    dim3 gTot((TOT_E + 255) / 256);
    dim3 gGemmN(NNP / 64);
    dim3 gGemmS(NSP / 64);
    dim3 gPrepH(PREP_BLOCKS + (TOT_E + 255) / 256);

    // ---- counts zero + fused prep/hist ----
    hipMemsetAsync(counts, 0, L_TOT * sizeof(int), stream);
    PrepHistArgs pa;
    pa.x = x; pa.xb = xb;
    pa.w[0] = Wm;  pa.w[1] = Wn2s0; pa.w[2] = Ws2n0; pa.w[3] = Wn2s1; pa.w[4] = Ws2n1;
    pa.wt[0] = wt0; pa.wt[1] = wt1; pa.wt[2] = wt2; pa.wt[3] = wt3; pa.wt[4] = wt4;
    pa.s0 = dst; pa.s1 = col0; pa.s2 = row0; pa.s3 = col1; pa.s4 = row1;
    pa.counts = counts; pa.rank = rank;
    pa.nE = N_E; pa.eS = E_S;
    preph_k<<<gPrepH, blk, 0, stream>>>(pa);

    // ---- scan + fill ----
    reduce_k<<<SCAN_NBLK, blk, 0, stream>>>(counts, bsums, L_TOT);
    scan_sums_k<<<1, blk, 0, stream>>>(bsums, SCAN_NBLK);
    scan_write_k<<<SCAN_NBLK, blk, 0, stream>>>(counts, bsums, offsets, L_TOT);
    fill5_k<<<gTot, blk, 0, stream>>>(dst, src, col0, row0, row0, col0,
                                      col1, row1, row1, col1, offsets, rank,
                                      perm, N_E, E_S);

    // ---- stage 1: h = relu((x + segsum(x[src] by dst)) @ Wm + bm) ----
    gg_k<<<gGemmN, blk, 0, stream>>>(xb, offB, perm, xb, wt0, bm,
                                     nullptr, nullptr, hbf, NN, 1);

    // ---- level 0 (output kept bf16-only in xb; residual Rb=hbf) ----
    gg_k<<<gGemmS, blk, 0, stream>>>(hbf, off0c, perm, nullptr, wt1, bn2s0,
                                     nullptr, nullptr, subb, NS, 0);
    gg_k<<<gGemmN, blk, 0, stream>>>(subb, off0r, perm, nullptr, wt2, bs2n0,
                                     hbf, nullptr, xb, NN, 0);

    // ---- level 1 (residual Rb=xb bf16; final fp32 out) ----
    gg_k<<<gGemmS, blk, 0, stream>>>(xb, off1c, perm, nullptr, wt3, bn2s1,
                                     nullptr, nullptr, subb, NS, 0);
    gg_k<<<gGemmN, blk, 0, stream>>>(subb, off1r, perm, nullptr, wt4, bs2n1,
                                     xb, out, nullptr, NN, 0);
}

// Round 11
// 343.491 us; speedup vs baseline: 1.0636x; 1.0636x over previous
//
#include <hip/hip_runtime.h>

#define D 128
#define NN 50000
#define NS 20000
#define NNP 50048              // padded to multiple of 64 rows
#define NSP 20032
#define L_TOT (3 * NN + 2 * NS)
#define SCAN_CHUNK 1024
#define SCAN_NBLK ((L_TOT + SCAN_CHUNK - 1) / SCAN_CHUNK)
#define LDA 136                // LDS row stride in bf16 elems

typedef short s16x8 __attribute__((ext_vector_type(8)));
typedef float f32x4 __attribute__((ext_vector_type(4)));

__device__ __forceinline__ float b2f(unsigned int u) {
    u <<= 16;
    float f; __builtin_memcpy(&f, &u, 4);
    return f;
}
__device__ __forceinline__ unsigned short f2b(float f) {
    unsigned int u; __builtin_memcpy(&u, &f, 4);
    u += 0x7fffu + ((u >> 16) & 1u);       // RNE
    return (unsigned short)(u >> 16);
}
__device__ __forceinline__ void acc8(float* a, uint4 v) {
    a[0] += b2f(v.x & 0xffffu); a[1] += b2f(v.x >> 16);
    a[2] += b2f(v.y & 0xffffu); a[3] += b2f(v.y >> 16);
    a[4] += b2f(v.z & 0xffffu); a[5] += b2f(v.z >> 16);
    a[6] += b2f(v.w & 0xffffu); a[7] += b2f(v.w >> 16);
}

// ---------------------------------------------------------------------------
// fused prep + hist. counts must be pre-zeroed (hipMemsetAsync).
// rank is u16 (max per-segment degree ~40 << 65536).
// ---------------------------------------------------------------------------
#define NX4 (NN * D / 4)                   // 1,600,000
#define NW  (5 * 16384)                    // 81,920
#define PREP_N (NX4 + NW)
#define PREP_BLOCKS ((PREP_N + 255) / 256) // 6570

struct PrepHistArgs {
    const float* x; unsigned short* xb;
    const float* w[5]; unsigned short* wt[5];
    const int* s0; const int* s1; const int* s2; const int* s3; const int* s4;
    int* counts; unsigned short* rank;
    int nE, eS;
};
__global__ __launch_bounds__(256) void preph_k(PrepHistArgs p)
{
    int bid = blockIdx.x;
    if (bid < PREP_BLOCKS) {
        int i = bid * 256 + threadIdx.x;
        if (i < NX4) {
            float4 v = ((const float4*)p.x)[i];
            ushort4 o;
            o.x = f2b(v.x); o.y = f2b(v.y); o.z = f2b(v.z); o.w = f2b(v.w);
            ((ushort4*)p.xb)[i] = o;
            return;
        }
        i -= NX4;
        if (i < NW) {
            int wi = i >> 14;
            int r  = i & 16383;
            int k = r >> 7, n = r & 127;
            p.wt[wi][n * 128 + k] = f2b(p.w[wi][k * 128 + n]);
        }
        return;
    }
    int e = (bid - PREP_BLOCKS) * 256 + threadIdx.x;
    int seg, base;
    if (e < p.nE) { seg = p.s0[e]; base = 0; }
    else {
        int r = e - p.nE;
        if      (r <     p.eS) { seg = p.s1[r];            base = NN; }
        else if (r < 2 * p.eS) { seg = p.s2[r - p.eS];     base = NN + NS; }
        else if (r < 3 * p.eS) { seg = p.s3[r - 2 * p.eS]; base = 2 * NN + NS; }
        else if (r < 4 * p.eS) { seg = p.s4[r - 3 * p.eS]; base = 2 * NN + 2 * NS; }
        else return;
    }
    p.rank[e] = (unsigned short)atomicAdd(&p.counts[base + seg], 1);
}

// ---------------------------------------------------------------------------
// scan over concatenated counts
// ---------------------------------------------------------------------------
__global__ __launch_bounds__(256) void reduce_k(const int* __restrict__ counts,
                                                int* __restrict__ blockSums, int n)
{
    __shared__ int lds[4];
    int tid = threadIdx.x;
    int base = blockIdx.x * SCAN_CHUNK;
    int s = 0;
    #pragma unroll
    for (int i = 0; i < 4; ++i) {
        int idx = base + tid + i * 256;
        if (idx < n) s += counts[idx];
    }
    #pragma unroll
    for (int off = 32; off > 0; off >>= 1) s += __shfl_down(s, off, 64);
    if ((tid & 63) == 0) lds[tid >> 6] = s;
    __syncthreads();
    if (tid == 0) blockSums[blockIdx.x] = lds[0] + lds[1] + lds[2] + lds[3];
}

__global__ __launch_bounds__(256) void scan_sums_k(int* __restrict__ blockSums, int nb)
{
    __shared__ int lds[256];
    int tid = threadIdx.x;
    lds[tid] = (tid < nb) ? blockSums[tid] : 0;
    __syncthreads();
    for (int off = 1; off < 256; off <<= 1) {
        int t = (tid >= off) ? lds[tid - off] : 0;
        __syncthreads();
        lds[tid] += t;
        __syncthreads();
    }
    if (tid < nb) blockSums[tid] = (tid > 0) ? lds[tid - 1] : 0;
}

__global__ __launch_bounds__(256) void scan_write_k(
    const int* __restrict__ counts, const int* __restrict__ blockSums,
    int* __restrict__ offsets, int n)
{
    __shared__ int lds[256];
    int tid = threadIdx.x;
    int base = blockIdx.x * SCAN_CHUNK + tid * 4;
    int v[4]; int s = 0;
    #pragma unroll
    for (int i = 0; i < 4; ++i) {
        int idx = base + i;
        int c = (idx < n) ? counts[idx] : 0;
        v[i] = c; s += c;
    }
    lds[tid] = s;
    __syncthreads();
    for (int off = 1; off < 256; off <<= 1) {
        int t = (tid >= off) ? lds[tid - off] : 0;
        __syncthreads();
        lds[tid] += t;
        __syncthreads();
    }
    int run = blockSums[blockIdx.x] + (tid > 0 ? lds[tid - 1] : 0);
    #pragma unroll
    for (int i = 0; i < 4; ++i) {
        int idx = base + i;
        run += v[i];
        if (idx < n) offsets[idx + 1] = run;
    }
    if (blockIdx.x == 0 && tid == 0) offsets[0] = 0;
}

__global__ __launch_bounds__(256) void fill5_k(
    const int* __restrict__ s0, const int* __restrict__ v0,
    const int* __restrict__ s1, const int* __restrict__ v1,
    const int* __restrict__ s2, const int* __restrict__ v2,
    const int* __restrict__ s3, const int* __restrict__ v3,
    const int* __restrict__ s4, const int* __restrict__ v4,
    const int* __restrict__ offsets, const unsigned short* __restrict__ rank,
    unsigned short* __restrict__ perm, int nE, int eS)
{
    int e = blockIdx.x * 256 + threadIdx.x;
    int seg, val, base;
    if (e < nE) { seg = s0[e]; val = v0[e]; base = 0; }
    else {
        int r = e - nE;
        if      (r <     eS) { seg = s1[r];          val = v1[r];          base = NN; }
        else if (r < 2 * eS) { seg = s2[r - eS];     val = v2[r - eS];     base = NN + NS; }
        else if (r < 3 * eS) { seg = s3[r - 2 * eS]; val = v3[r - 2 * eS]; base = 2 * NN + NS; }
        else if (r < 4 * eS) { seg = s4[r - 3 * eS]; val = v4[r - 3 * eS]; base = 2 * NN + 2 * NS; }
        else return;
    }
    perm[offsets[base + seg] + (int)rank[e]] = (unsigned short)val;
}

// ---------------------------------------------------------------------------
// Fused gather + MFMA GEMM, low-LDS (a_lds only, 17.4 KB, 7 blocks/CU).
// R9 configuration: x4 edge unroll, 16 lanes/segment, bounds (256,7).
// perm is u16 (node/sub ids < 65536).
// ---------------------------------------------------------------------------
__global__ __launch_bounds__(256, 7) void gg_k(
    const unsigned short* __restrict__ feat, const int* __restrict__ offsets,
    const unsigned short* __restrict__ perm, const unsigned short* __restrict__ addend,
    const unsigned short* __restrict__ Wt, const float* __restrict__ bias,
    const unsigned short* __restrict__ Rb,
    float* __restrict__ outF, unsigned short* __restrict__ outB,
    int M, int relu)
{
    __shared__ unsigned short a_lds[64 * LDA];    // 17.4 KB

    const int tid = threadIdx.x;
    const int r0  = blockIdx.x * 64;

    // gather 64 rows: 4 passes x (16 segments x 16 lanes)
    const uint4* f4 = (const uint4*)feat;         // one row = 16 uint4
    const int lane16 = tid & 15;
    #pragma unroll
    for (int p = 0; p < 4; ++p) {
        int rloc = p * 16 + (tid >> 4);
        int s = r0 + rloc;
        float a[8] = {0.f, 0.f, 0.f, 0.f, 0.f, 0.f, 0.f, 0.f};
        if (s < M) {
            float b[8] = {0.f, 0.f, 0.f, 0.f, 0.f, 0.f, 0.f, 0.f};
            if (addend) {
                uint4 v = ((const uint4*)(addend + (size_t)s * D))[lane16];
                acc8(a, v);
            }
            int beg = offsets[s], end = offsets[s + 1];
            int j = beg;
            for (; j + 3 < end; j += 4) {
                int e0 = perm[j], e1 = perm[j + 1], e2 = perm[j + 2], e3 = perm[j + 3];
                uint4 v0 = f4[(size_t)e0 * 16 + lane16];
                uint4 v1 = f4[(size_t)e1 * 16 + lane16];
                uint4 v2 = f4[(size_t)e2 * 16 + lane16];
                uint4 v3 = f4[(size_t)e3 * 16 + lane16];
                acc8(a, v0); acc8(b, v1); acc8(a, v2); acc8(b, v3);
            }
            for (; j < end; ++j)
                acc8(a, f4[(size_t)perm[j] * 16 + lane16]);
            #pragma unroll
            for (int i = 0; i < 8; ++i) a[i] += b[i];
        }
        uint4 o;
        o.x = (unsigned int)f2b(a[0]) | ((unsigned int)f2b(a[1]) << 16);
        o.y = (unsigned int)f2b(a[2]) | ((unsigned int)f2b(a[3]) << 16);
        o.z = (unsigned int)f2b(a[4]) | ((unsigned int)f2b(a[5]) << 16);
        o.w = (unsigned int)f2b(a[6]) | ((unsigned int)f2b(a[7]) << 16);
        *((uint4*)&a_lds[rloc * LDA + lane16 * 8]) = o;
    }
    __syncthreads();

    const int lane = tid & 63;
    const int w    = tid >> 6;
    const int ln   = lane & 15;
    const int quad = lane >> 4;

    s16x8 af[4];
    const unsigned short* arow = &a_lds[(w * 16 + ln) * LDA + quad * 8];
    #pragma unroll
    for (int kc = 0; kc < 4; ++kc)
        af[kc] = *((const s16x8*)(arow + kc * 32));

    const int rbase = r0 + w * 16 + quad * 4;
    const s16x8* wt8 = (const s16x8*)Wt;          // row = 16 x s16x8

    #pragma unroll
    for (int nt = 0; nt < 8; ++nt) {
        f32x4 acc = {0.f, 0.f, 0.f, 0.f};
        const s16x8* brow = wt8 + (nt * 16 + ln) * 16 + quad;
        #pragma unroll
        for (int kc = 0; kc < 4; ++kc) {
            s16x8 bf = brow[kc * 4];              // global, L2-hit
            acc = __builtin_amdgcn_mfma_f32_16x16x32_bf16(af[kc], bf, acc, 0, 0, 0);
        }
        int col = nt * 16 + ln;
        float bc = bias[col];
        #pragma unroll
        for (int r = 0; r < 4; ++r) {
            int row = rbase + r;
            if (row < M) {
                float v = acc[r] + bc;
                size_t gi = (size_t)row * D + col;
                if (Rb) v += b2f((unsigned int)Rb[gi]);
                if (relu) v = fmaxf(v, 0.f);
                if (outF) outF[gi] = v;
                if (outB) outB[gi] = f2b(v);
            }
        }
    }
}

// ---------------------------------------------------------------------------
extern "C" void kernel_launch(void* const* d_in, const int* in_sizes, int n_in,
                              void* d_out, int out_size, void* d_ws, size_t ws_size,
                              hipStream_t stream)
{
    const float* x     = (const float*)d_in[0];
    const float* Wm    = (const float*)d_in[1];
    const float* bm    = (const float*)d_in[2];
    const float* Wn2s0 = (const float*)d_in[3];
    const float* bn2s0 = (const float*)d_in[4];
    const float* Ws2n0 = (const float*)d_in[5];
    const float* bs2n0 = (const float*)d_in[6];
    const float* Wn2s1 = (const float*)d_in[7];
    const float* bn2s1 = (const float*)d_in[8];
    const float* Ws2n1 = (const float*)d_in[9];
    const float* bs2n1 = (const float*)d_in[10];
    const int* nei  = (const int*)d_in[11];
    const int* row0 = (const int*)d_in[12];
    const int* col0 = (const int*)d_in[13];
    const int* row1 = (const int*)d_in[14];
    const int* col1 = (const int*)d_in[15];

    const int N_E = in_sizes[11] / 2;  // 600000
    const int E_S = in_sizes[12];      // 120000
    const int TOT_E = N_E + 4 * E_S;

    const int* src = nei;
    const int* dst = nei + N_E;

    float* out = (float*)d_out;

    // ---- workspace layout ----
    unsigned short* xb   = (unsigned short*)d_ws;          // x bf16 / out_l0 bf16
    unsigned short* hbf  = xb  + (size_t)NNP * D;          // h bf16 (residual)
    unsigned short* subb = hbf + (size_t)NNP * D;          // sub bf16
    unsigned short* wtb  = subb + (size_t)NSP * D;         // 5 transposed bf16 W
    unsigned short* rank = wtb + 5 * 16384;                // u16, TOT_E
    unsigned short* perm = rank + ((TOT_E + 1) & ~1);      // u16, TOT_E
    int* ip      = (int*)(perm + ((TOT_E + 1) & ~1));
    int* counts  = ip;              ip += L_TOT;
    int* offsets = ip;              ip += L_TOT + 1;
    int* bsums   = ip;              ip += 256;

    unsigned short* wt0 = wtb;
    unsigned short* wt1 = wtb + 16384;
    unsigned short* wt2 = wtb + 2 * 16384;
    unsigned short* wt3 = wtb + 3 * 16384;
    unsigned short* wt4 = wtb + 4 * 16384;

    const int* offB  = offsets;
    const int* off0c = offsets + NN;
    const int* off0r = offsets + NN + NS;
    const int* off1c = offsets + 2 * NN + NS;
    const int* off1r = offsets + 2 * NN + 2 * NS;

    dim3 blk(256);
    dim3 gTot((TOT_E + 255) / 256);
    dim3 gGemmN(NNP / 64);
    dim3 gGemmS(NSP / 64);
    dim3 gPrepH(PREP_BLOCKS + (TOT_E + 255) / 256);

    // ---- counts zero + fused prep/hist ----
    hipMemsetAsync(counts, 0, L_TOT * sizeof(int), stream);
    PrepHistArgs pa;
    pa.x = x; pa.xb = xb;
    pa.w[0] = Wm;  pa.w[1] = Wn2s0; pa.w[2] = Ws2n0; pa.w[3] = Wn2s1; pa.w[4] = Ws2n1;
    pa.wt[0] = wt0; pa.wt[1] = wt1; pa.wt[2] = wt2; pa.wt[3] = wt3; pa.wt[4] = wt4;
    pa.s0 = dst; pa.s1 = col0; pa.s2 = row0; pa.s3 = col1; pa.s4 = row1;
    pa.counts = counts; pa.rank = rank;
    pa.nE = N_E; pa.eS = E_S;
    preph_k<<<gPrepH, blk, 0, stream>>>(pa);

    // ---- scan + fill ----
    reduce_k<<<SCAN_NBLK, blk, 0, stream>>>(counts, bsums, L_TOT);
    scan_sums_k<<<1, blk, 0, stream>>>(bsums, SCAN_NBLK);
    scan_write_k<<<SCAN_NBLK, blk, 0, stream>>>(counts, bsums, offsets, L_TOT);
    fill5_k<<<gTot, blk, 0, stream>>>(dst, src, col0, row0, row0, col0,
                                      col1, row1, row1, col1, offsets, rank,
                                      perm, N_E, E_S);

    // ---- stage 1: h = relu((x + segsum(x[src] by dst)) @ Wm + bm) ----
    gg_k<<<gGemmN, blk, 0, stream>>>(xb, offB, perm, xb, wt0, bm,
                                     nullptr, nullptr, hbf, NN, 1);

    // ---- level 0 (output kept bf16-only in xb; residual Rb=hbf) ----
    gg_k<<<gGemmS, blk, 0, stream>>>(hbf, off0c, perm, nullptr, wt1, bn2s0,
                                     nullptr, nullptr, subb, NS, 0);
    gg_k<<<gGemmN, blk, 0, stream>>>(subb, off0r, perm, nullptr, wt2, bs2n0,
                                     hbf, nullptr, xb, NN, 0);

    // ---- level 1 (residual Rb=xb bf16; final fp32 out) ----
    gg_k<<<gGemmS, blk, 0, stream>>>(xb, off1c, perm, nullptr, wt3, bn2s1,
                                     nullptr, nullptr, subb, NS, 0);
    gg_k<<<gGemmN, blk, 0, stream>>>(subb, off1r, perm, nullptr, wt4, bs2n1,
                                     xb, out, nullptr, NN, 0);
}